// Round 1
// 153.816 us; speedup vs baseline: 1.1473x; 1.1473x over previous
//
#include <hip/hip_runtime.h>
#include <math.h>

// Problem constants (B, CIN, COUT, K, S, P, D) = (4,128,128,3,1,1,1), H=W=96
#define HH 96
#define WW 96
#define HW (96*96)
#define CIN_ 128
#define COUT_ 128
#define OUT_ELEMS (4*128*96*96)
#define TPX 48            // pixels per block: 192*4 = 768 blocks = exactly 3/CU

// ws layout (bytes)
#define XT_OFF   0u           // x_t bf16 [4][9216][128] = 9,437,184 B
#define WBF_OFF  9437184u     // wbf bf16 [128][1152] (q=kc*128+c) = 294,912 B
#define WOMB_OFF 9732096u     // womb bf16 [32][1152] (rows>=27 zero) = 73,728 B

typedef __attribute__((ext_vector_type(8))) short short8v;
typedef __attribute__((ext_vector_type(4))) float float4v;

__device__ __forceinline__ unsigned short f2bf(float f) {
    unsigned u = __builtin_bit_cast(unsigned, f);
    u += 0x7FFFu + ((u >> 16) & 1u);   // RNE (inputs finite)
    return (unsigned short)(u >> 16);
}
__device__ __forceinline__ float bflo(unsigned u) {
    return __builtin_bit_cast(float, u << 16);
}
__device__ __forceinline__ float bfhi(unsigned u) {
    return __builtin_bit_cast(float, u & 0xffff0000u);
}

// ---------------------------------------------------------------------------
// Merged prep: blocks [0,576) transpose x -> x_t bf16; blocks [576,1296)
// convert weights to bf16 (q reordered to kc*128+c; wom padded to 32 rows).
// ---------------------------------------------------------------------------
__global__ __launch_bounds__(256) void pre_kernel(
    const float* __restrict__ x, const float* __restrict__ w,
    const float* __restrict__ wom, unsigned short* __restrict__ xt,
    unsigned short* __restrict__ wbf, unsigned short* __restrict__ womb)
{
    __shared__ float tile[64][130];
    const int t = threadIdx.x;

    if (blockIdx.x < 576) {
        const int b  = blockIdx.x / 144;
        const int p0 = (blockIdx.x - b * 144) * 64;
#pragma unroll
        for (int j = 0; j < 8; j++) {           // read: 4 px per thread (float4)
            const int i  = j * 256 + t;
            const int c  = i >> 4;
            const int p4 = (i & 15) * 4;
            const float4 v = *(const float4*)(x + ((size_t)(b * CIN_ + c) * HW + p0 + p4));
            tile[p4 + 0][c] = v.x; tile[p4 + 1][c] = v.y;
            tile[p4 + 2][c] = v.z; tile[p4 + 3][c] = v.w;
        }
        __syncthreads();
#pragma unroll
        for (int j = 0; j < 8; j++) {           // write: 4 c per thread (8 B bf16)
            const int i   = j * 256 + t;
            const int pxl = i >> 5;
            const int c4  = (i & 31) * 4;
            uint2 v;
            v.x = (unsigned)f2bf(tile[pxl][c4 + 0]) | ((unsigned)f2bf(tile[pxl][c4 + 1]) << 16);
            v.y = (unsigned)f2bf(tile[pxl][c4 + 2]) | ((unsigned)f2bf(tile[pxl][c4 + 3]) << 16);
            *(uint2*)(xt + ((size_t)(b * HW + p0 + pxl) * CIN_ + c4)) = v;
        }
    } else {
        const int i = (blockIdx.x - 576) * 256 + t;
        if (i < COUT_ * 1152) {
            const int oc = i / 1152, r = i - oc * 1152;
            const int kc = r >> 7, c = r & 127;
            wbf[i] = f2bf(w[(size_t)oc * 1152 + c * 9 + kc]);
        } else {
            const int i2 = i - COUT_ * 1152;
            if (i2 < 32 * 1152) {
                const int row = i2 / 1152, r = i2 - row * 1152;
                const int kc = r >> 7, c = r & 127;
                womb[i2] = (row < 27) ? f2bf(wom[(size_t)row * 1152 + c * 9 + kc]) : 0;
            }
        }
    }
}

// ---------------------------------------------------------------------------
// Fused kernel: om GEMM (27x48 tile, in-LDS) -> sampling prep -> deformable
// gather + main MFMA GEMM + bias.  Grid (192,4), 512 thr, 48 px / block.
//   phase 0: waves 0..5 compute om = womb @ x_t for this block's 48 px
//            (B-frags direct from global x_t, per-lane border predication);
//            results -> som (LDS), rows<18 also -> off_out (global).
//   phase 1: 432 threads build sprep (bilinear corners + mask*weights).
//   phase 2: per kc {gather -> swizzled btile[kc&1], barrier, MFMA}, with
//            double-buffered btile (1 barrier per kc) and A-frags hoisted
//            above the gather.
// btile layout: per px a 256 B row of 16x 16B chunks, chunk index
// c16 ^= (px&7)  ->  conflict-free ds_read_b128 AND conflict-free writes.
// LDS: sprep 13824 + btile 2*12288 = 38400 B (som aliases btile[0]).
// ---------------------------------------------------------------------------
__global__ __launch_bounds__(512, 6) void dconv_fused(
    const unsigned short* __restrict__ xt, const unsigned short* __restrict__ wbf,
    const unsigned short* __restrict__ womb, const float* __restrict__ bias,
    float* __restrict__ out, float* __restrict__ off_out)
{
    __shared__ int sprep[432 * 8];          // 13824 B
    __shared__ int btile[2][TPX * 64];      // 24576 B
    float* som = (float*)&btile[0][0];      // [27][TPX] floats, 5184 B (alias)

    const int t    = threadIdx.x;
    const int wave = __builtin_amdgcn_readfirstlane(t >> 6);
    const int lane = t & 63;
    const int quad = lane >> 4;
    const int m    = lane & 15;
    const int b    = blockIdx.y;
    const int p0   = blockIdx.x * TPX;

    const unsigned short* xtb = xt + (size_t)b * HW * CIN_;

    // ---- phase 0: offset/mask conv for this block's own pixels ------------
    if (wave < 6) {
        const int pxg = wave >> 1;          // 0..2  (16-px group)
        const int mt  = wave & 1;           // 0..1  (16-row m-tile)
        const int pgl = pxg * 16 + m;       // 0..47 local pixel
        const int pg  = p0 + pgl;
        const int h   = pg / 96;
        const int w   = pg - h * 96;

        float4v acc2;
#pragma unroll
        for (int r = 0; r < 4; r++) acc2[r] = 0.f;
        const short8v zerov = (short8v)0;

#pragma unroll
        for (int kc = 0; kc < 9; kc++) {
            const int ki = kc / 3, kj = kc - 3 * (kc / 3);
            const int y  = h + ki - 1, xx = w + kj - 1;
            const bool valid = ((unsigned)y < 96u) && ((unsigned)xx < 96u);
            const unsigned short* brow = xtb + (size_t)(y * 96 + xx) * CIN_ + quad * 8;
            const short* abase = (const short*)womb + (size_t)(mt * 16 + m) * 1152 + kc * 128 + quad * 8;
#pragma unroll
            for (int kst = 0; kst < 4; kst++) {
                const short8v bfv = valid ? *(const short8v*)(brow + kst * 32) : zerov;
                const short8v av  = *(const short8v*)(abase + kst * 32);
                acc2 = __builtin_amdgcn_mfma_f32_16x16x32_bf16(av, bfv, acc2, 0, 0, 0);
            }
        }
#pragma unroll
        for (int r = 0; r < 4; r++) {
            const int oc = mt * 16 + quad * 4 + r;
            if (oc < 27) som[oc * TPX + pgl] = acc2[r];
            if (oc < 18) off_out[(size_t)(b * 18 + oc) * HW + pg] = acc2[r];
        }
    }
    __syncthreads();

    // ---- phase 1: sampling prep (reads som, writes sprep) -----------------
    if (t < 432) {
        const int kc  = t / 48;
        const int pxl = t - kc * 48;
        const int pg  = p0 + pxl;
        const int h   = pg / 96;
        const int w   = pg - h * 96;
        const int ki  = kc / 3, kj = kc - 3 * (kc / 3);

        const float o1 = som[kc * TPX + pxl];
        const float o2 = som[(9 + kc) * TPX + pxl];
        const float mr = som[(18 + kc) * TPX + pxl];
        const float mk = 2.f / (1.f + __expf(-mr));   // sigmoid * MASK_SCALE

        const float py = (float)(h - 1 + ki) + o1;
        const float px = (float)(w - 1 + kj) + o2;
        const float y0f = floorf(py), x0f = floorf(px);
        const float ly = py - y0f,    lx = px - x0f;
        const int y0 = (int)y0f, x0 = (int)x0f;
        const int y1 = y0 + 1,   x1 = x0 + 1;

        const float w00 = (1.f - ly) * (1.f - lx), w01 = (1.f - ly) * lx;
        const float w10 = ly * (1.f - lx),         w11 = ly * lx;

        const int yc0 = min(max(y0, 0), HH - 1), yc1 = min(max(y1, 0), HH - 1);
        const int xc0 = min(max(x0, 0), WW - 1), xc1 = min(max(x1, 0), WW - 1);
        const bool vy0 = (y0 >= 0) && (y0 < HH), vy1 = (y1 >= 0) && (y1 < HH);
        const bool vx0 = (x0 >= 0) && (x0 < WW), vx1 = (x1 >= 0) && (x1 < WW);

        sprep[t * 8 + 0] = yc0 * 96 + xc0;
        sprep[t * 8 + 1] = yc0 * 96 + xc1;
        sprep[t * 8 + 2] = yc1 * 96 + xc0;
        sprep[t * 8 + 3] = yc1 * 96 + xc1;
        sprep[t * 8 + 4] = __builtin_bit_cast(int, (vy0 && vx0) ? mk * w00 : 0.f);
        sprep[t * 8 + 5] = __builtin_bit_cast(int, (vy0 && vx1) ? mk * w01 : 0.f);
        sprep[t * 8 + 6] = __builtin_bit_cast(int, (vy1 && vx0) ? mk * w10 : 0.f);
        sprep[t * 8 + 7] = __builtin_bit_cast(int, (vy1 && vx1) ? mk * w11 : 0.f);
    }
    __syncthreads();

    // ---- phase 2: gather + main GEMM, double-buffered btile ---------------
    float4v acc[3];
#pragma unroll
    for (int j = 0; j < 3; j++)
#pragma unroll
        for (int r = 0; r < 4; r++) acc[j][r] = 0.f;

    for (int kc = 0; kc < 9; kc++) {
        int* bt = &btile[kc & 1][0];

        // A-fragments for this kc (global, L1/L2-hot) — hoisted above gather
        const short* abase = (const short*)wbf + (size_t)(wave * 16 + m) * 1152 + kc * 128 + quad * 8;
        short8v af[4];
#pragma unroll
        for (int kst = 0; kst < 4; kst++)
            af[kst] = *(const short8v*)(abase + kst * 32);

        // gather: wave-per-pixel, lane = 2 channels (bf16 pair = 4 B)
#pragma unroll
        for (int p = 0; p < 6; p++) {
            const int pxl = p * 8 + wave;
            const int s   = kc * 48 + pxl;
            const int4   id4 = *(const int4*)&sprep[s * 8];
            const float4 w4  = *(const float4*)&sprep[s * 8 + 4];
            const unsigned u0 = *(const unsigned*)(xtb + (size_t)id4.x * CIN_ + 2 * lane);
            const unsigned u1 = *(const unsigned*)(xtb + (size_t)id4.y * CIN_ + 2 * lane);
            const unsigned u2 = *(const unsigned*)(xtb + (size_t)id4.z * CIN_ + 2 * lane);
            const unsigned u3 = *(const unsigned*)(xtb + (size_t)id4.w * CIN_ + 2 * lane);
            const float vx = w4.x * bflo(u0) + w4.y * bflo(u1) + w4.z * bflo(u2) + w4.w * bflo(u3);
            const float vy = w4.x * bfhi(u0) + w4.y * bfhi(u1) + w4.z * bfhi(u2) + w4.w * bfhi(u3);
            // swizzled write: 16B-chunk index (lane>>2) XOR (pxl&7)
            bt[pxl * 64 + (((lane >> 2) ^ (pxl & 7)) << 2) + (lane & 3)] =
                (int)((unsigned)f2bf(vx) | ((unsigned)f2bf(vy) << 16));
        }
        __syncthreads();

        // MFMA: wave = 16-oc slice; 4 kst x 3 nt; conflict-free swizzled reads
#pragma unroll
        for (int kst = 0; kst < 4; kst++) {
#pragma unroll
            for (int nt = 0; nt < 3; nt++) {
                const int pxl = nt * 16 + m;
                const short8v bfv = *(const short8v*)((const short*)bt
                    + 2 * (pxl * 64 + (((kst * 4 + quad) ^ (m & 7)) << 2)));
                acc[nt] = __builtin_amdgcn_mfma_f32_16x16x32_bf16(af[kst], bfv, acc[nt], 0, 0, 0);
            }
        }
        // no trailing barrier: next gather writes the other buffer
    }

    // ---- epilogue ---------------------------------------------------------
#pragma unroll
    for (int r = 0; r < 4; r++) {
        const int oc = wave * 16 + quad * 4 + r;
        const float bv = bias[oc];
#pragma unroll
        for (int nt = 0; nt < 3; nt++)
            out[(size_t)(b * COUT_ + oc) * HW + p0 + nt * 16 + m] = acc[nt][r] + bv;
    }
}

extern "C" void kernel_launch(void* const* d_in, const int* in_sizes, int n_in,
                              void* d_out, int out_size, void* d_ws, size_t ws_size,
                              hipStream_t stream) {
    const float* x      = (const float*)d_in[0];
    const float* weight = (const float*)d_in[1];
    const float* bias   = (const float*)d_in[2];
    const float* wom    = (const float*)d_in[3];

    float* out     = (float*)d_out;
    float* off_out = out + OUT_ELEMS;

    unsigned short* xtb  = (unsigned short*)((char*)d_ws + XT_OFF);
    unsigned short* wbf  = (unsigned short*)((char*)d_ws + WBF_OFF);
    unsigned short* womb = (unsigned short*)((char*)d_ws + WOMB_OFF);

    pre_kernel <<<dim3(1296),   256, 0, stream>>>(x, weight, wom, xtb, wbf, womb);
    dconv_fused<<<dim3(192, 4), 512, 0, stream>>>(xtb, wbf, womb, bias, out, off_out);
}